// Round 3
// baseline (7616.904 us; speedup 1.0000x reference)
//
#include <hip/hip_runtime.h>
#include <cstdint>

typedef _Float16 f16;
typedef _Float16 f16x8 __attribute__((ext_vector_type(8)));
typedef float    f32x4 __attribute__((ext_vector_type(4)));

#define DINL __device__ __forceinline__

static constexpr int HID = 1024;
static constexpr int NG  = 4096;   // 4*HID gate count
static constexpr int BB  = 256;    // batch
static constexpr int TT  = 100;    // seq len
static constexpr int KX  = 256;    // padded input-feature K (227 -> 256)
static constexpr size_t MSZ = (size_t)NG * HID;   // halves per packed [4096][1024] mat

// ---- workspace layout (bytes). total ~119 MiB ----
static constexpr size_t OFF_PACKW5 = 0;
static constexpr size_t OFF_W1D    = OFF_PACKW5 + 5*MSZ*2;
static constexpr size_t OFF_WIH1   = OFF_W1D   + MSZ*2;
static constexpr size_t OFF_WD     = OFF_WIH1  + (size_t)NG*KX*2;
static constexpr size_t OFF_XPAD   = OFF_WD    + (size_t)256*HID*2;
static constexpr size_t OFF_BIAS   = OFF_XPAD  + (size_t)TT*BB*KX*2;
static constexpr size_t OFF_C      = OFF_BIAS  + (size_t)4*NG*4;
static constexpr size_t OFF_HBUF   = OFF_C     + (size_t)3*BB*HID*4;
static constexpr size_t OFF_H2Z    = OFF_HBUF  + (size_t)4*BB*HID*2;
static constexpr size_t OFF_H2ALL  = OFF_H2Z   + (size_t)BB*HID*2;
// WdT scratch ([1024][256] f16) lives at OFF_H2ALL until k_w1d consumes it.

DINL void async16(void* lds, const void* g){
  auto lp = reinterpret_cast<__attribute__((address_space(3))) unsigned int*>(
      reinterpret_cast<uintptr_t>(lds));
  auto gp = reinterpret_cast<const __attribute__((address_space(1))) unsigned int*>(
      reinterpret_cast<uintptr_t>(g));
  __builtin_amdgcn_global_load_lds(gp, lp, 16, 0, 0);
}

// LDS read via inline asm: invisible to the compiler's LDS-DMA waitcnt pass.
DINL f16x8 ldsr128(unsigned a){
  f16x8 r;
  asm volatile("ds_read_b128 %0, %1" : "=v"(r) : "v"(a));
  return r;
}

// direct global->VGPR B-fragment load: SGPR base + per-lane 32-bit voffset.
DINL f16x8 gload(unsigned voff, const f16* sbase){
  f16x8 r;
  asm volatile("global_load_dwordx4 %0, %1, %2"
    : "=v"(r) : "v"(voff), "s"(sbase));
  return r;
}

DINL float sigf(float x){
  x = fminf(fmaxf(x, -30.f), 30.f);
  return __fdividef(1.f, 1.f + __expf(-x));
}
DINL float tanh_fast(float x){
  x = fminf(fmaxf(x, -15.f), 15.f);
  float t = __expf(2.f*x);
  return __fdividef(t - 1.f, t + 1.f);
}

// ---- single-buffered 128x128 tile core (k_w1d / k_final only) ----
DINL void gemm_tile(f32x4 acc[4][4],
                    const f16* __restrict__ A, int m0, int sA,
                    const f16* __restrict__ Bp, int n0, int K,
                    char* ldsA, char* ldsB, int w, int lane)
{
  const int m_w = (w>>1)*64, n_w = (w&1)*64, c15 = lane&15;
  for (int k0 = 0; k0 < K; k0 += 64){
    __syncthreads();
    #pragma unroll
    for (int q = 0; q < 4; q++){
      int r0  = w*32 + q*8;
      int row = r0 + (lane>>3);
      int kg  = (lane&7) ^ (row&7);
      async16(ldsA + r0*128, A  + (size_t)(m0+row)*sA + k0 + kg*8);
      async16(ldsB + r0*128, Bp + (size_t)(n0+row)*K  + k0 + kg*8);
    }
    __syncthreads();
    #pragma unroll
    for (int kw = 0; kw < 2; kw++){
      f16x8 af[4], bf[4];
      #pragma unroll
      for (int ti = 0; ti < 4; ti++){
        int row  = m_w + ti*16 + c15;
        int phys = (kw*4 + (lane>>4)) ^ (row&7);
        af[ti] = *(const f16x8*)(ldsA + row*128 + phys*16);
      }
      #pragma unroll
      for (int tj = 0; tj < 4; tj++){
        int row  = n_w + tj*16 + c15;
        int phys = (kw*4 + (lane>>4)) ^ (row&7);
        bf[tj] = *(const f16x8*)(ldsB + row*128 + phys*16);
      }
      #pragma unroll
      for (int ti = 0; ti < 4; ti++)
        #pragma unroll
        for (int tj = 0; tj < 4; tj++)
          acc[ti][tj] = __builtin_amdgcn_mfma_f32_16x16x32_f16(af[ti], bf[tj], acc[ti][tj], 0, 0, 0);
    }
  }
}

// ================= prep kernels =================

__global__ void k_pack5(const float* W0, const float* W1, const float* W2,
                        const float* W3, const float* W4, char* ws)
{
  f16* dst = (f16*)(ws + OFF_PACKW5);
  const int mat = blockIdx.y;
  const float* src = mat==0?W0 : mat==1?W1 : mat==2?W2 : mat==3?W3 : W4;
  int tid = blockIdx.x*256 + threadIdx.x;
  int n = tid >> 7, kc = tid & 127;
  int r = ((n&3) << 10) + (n >> 2);
  const float* s = src + (size_t)r*HID + kc*8;
  f16x8 o;
  #pragma unroll
  for (int i = 0; i < 8; i++) o[i] = (f16)s[i];
  *(f16x8*)(dst + (size_t)mat*MSZ + (size_t)n*HID + kc*8) = o;
}

__global__ void k_packwih1(const float* __restrict__ Wih1, char* ws){
  f16* dst = (f16*)(ws + OFF_WIH1);
  int n = blockIdx.x, k = threadIdx.x;
  int r = ((n&3) << 10) + (n >> 2);
  dst[(size_t)n*KX + k] = (k < 227) ? (f16)Wih1[(size_t)r*227 + k] : (f16)0.f;
}

__global__ void k_packwd(const float* __restrict__ Wd, char* ws){
  f16* dst = (f16*)(ws + OFF_WD);
  int o = blockIdx.x;
  #pragma unroll
  for (int j = 0; j < 4; j++){
    int k = threadIdx.x + j*256;
    dst[(size_t)o*HID + k] = (o < 227) ? (f16)Wd[(size_t)o*HID + k] : (f16)0.f;
  }
}

__global__ void k_packwdt(const float* __restrict__ Wd, char* ws){
  f16* dst = (f16*)(ws + OFF_H2ALL);
  int h = blockIdx.x, o = threadIdx.x;
  dst[(size_t)h*KX + o] = (o < 227) ? (f16)Wd[(size_t)o*HID + h] : (f16)0.f;
}

__global__ void k_xpad(const float* __restrict__ seq, char* ws){
  f16* dst = (f16*)(ws + OFF_XPAD);
  int idx = blockIdx.x*256 + threadIdx.x;
  int t = idx >> 16, rem = idx & 65535, b = rem >> 8, k = rem & 255;
  dst[idx] = (k < 227) ? (f16)seq[(size_t)b*22700 + (size_t)t*227 + k] : (f16)0.f;
}

__global__ void k_bias(const float* bih1, const float* bhh1, const float* bih2, const float* bhh2,
                       const float* bih3, const float* bhh3, const float* Wih1, const float* bd,
                       char* ws)
{
  int n = blockIdx.x*256 + threadIdx.x;
  if (n >= NG) return;
  int r = ((n&3) << 10) + (n >> 2);
  float* b = (float*)(ws + OFF_BIAS);
  float bf = bih1[r] + bhh1[r];
  float s = 0.f;
  for (int o = 0; o < 227; o++) s += Wih1[(size_t)r*227 + o] * bd[o];
  b[n]        = bf;
  b[NG + n]   = bf + s;
  b[2*NG + n] = bih2[r] + bhh2[r];
  b[3*NG + n] = bih3[r] + bhh3[r];
}

__global__ __launch_bounds__(256, 2) void k_w1d(char* ws)
{
  __shared__ __align__(16) char ldsA[16384];
  __shared__ __align__(16) char ldsB[16384];
  const int w = threadIdx.x >> 6, lane = threadIdx.x & 63;
  const int n0 = blockIdx.x*128, m0 = blockIdx.y*128;
  const f16* A  = (const f16*)(ws + OFF_WIH1);
  const f16* Bp = (const f16*)(ws + OFF_H2ALL);
  f16* W1D = (f16*)(ws + OFF_W1D);

  f32x4 acc[4][4];
  f32x4 zero = {0.f, 0.f, 0.f, 0.f};
  #pragma unroll
  for (int i = 0; i < 4; i++)
    #pragma unroll
    for (int j = 0; j < 4; j++) acc[i][j] = zero;

  gemm_tile(acc, A, m0, KX, Bp, n0, KX, ldsA, ldsB, w, lane);

  const int m_w = (w>>1)*64, n_w = (w&1)*64, quad = lane>>4, c15 = lane&15;
  #pragma unroll
  for (int tj = 0; tj < 4; tj++){
    int col = n0 + n_w + tj*16 + c15;
    #pragma unroll
    for (int ti = 0; ti < 4; ti++){
      f32x4 v = acc[ti][tj];
      #pragma unroll
      for (int r = 0; r < 4; r++){
        int m = m0 + m_w + ti*16 + quad*4 + r;
        W1D[(size_t)m*HID + col] = (f16)v[r];
      }
    }
  }
}

// ================= recurrent step kernel =================
// grid (64 ntiles, 3 layers), 512 threads = 8 waves (2/SIMD).
// Tm=256 x Tn=64, BK=64; wave tile 32x64. NO barriers in the K-loop:
//   A (h-state): per-wave-private 4x4KB LDS buffers via global_load_lds (128KB total).
//   B (weights): direct global->VGPR fragments, 4-deep static register buffers;
//                the 8-wave same-line redundancy is absorbed by L1 (8KB/iter window).
// Unified per-wave vmcnt pipeline: 12 vm-ops/stage (4 A-DMA + 8 B-loads), depth 4.
// Issue stage c+4 AFTER the MFMAs of stage c (WAR-safe, in-order issue).
// Waits: steady vmcnt(36); tail 24/12/0. lgkm: 2 then 0 for the 4 A ds_reads.
// Raw s_barrier every 8 iters only to bound wave skew (keeps L1 multicast hot).
__global__ __launch_bounds__(512, 2) void k_step(char* __restrict__ ws, int t, int use_gt)
{
  __shared__ __align__(16) char lds[131072];
  const int w = threadIdx.x >> 6, lane = threadIdx.x & 63;
  const int col0 = blockIdx.x*64, layer = blockIdx.y;

  const f16* packW = (const f16*)(ws + OFF_PACKW5);
  const f16* W1D   = (const f16*)(ws + OFF_W1D);
  const f16* WIH1  = (const f16*)(ws + OFF_WIH1);
  const f16* XP    = (const f16*)(ws + OFF_XPAD) + (size_t)t*BB*KX;
  const float* biasb = (const float*)(ws + OFF_BIAS);
  float* Cst = (float*)(ws + OFF_C);
  f16* HB  = (f16*)(ws + OFF_HBUF);
  f16* H2Z = (f16*)(ws + OFF_H2Z);
  f16* H2A = (f16*)(ws + OFF_H2ALL);

  const int pr = t & 1, pw = pr ^ 1;
  const f16* h0p = HB + (size_t)(pr*2 + 0)*BB*HID;
  const f16* h1p = HB + (size_t)(pr*2 + 1)*BB*HID;
  const f16* h2p = (t == 0) ? H2Z : (H2A + (size_t)(t-1)*BB*HID);

  const f16 *A0, *A1, *B0, *B1; int K1, sA1;
  const float* biasp; f16* hout; float* cptr;
  if (layer == 0){
    A0 = h0p; B0 = packW;
    if (use_gt){ A1 = XP;  B1 = WIH1; K1 = KX;  sA1 = KX;  biasp = biasb; }
    else       { A1 = h2p; B1 = W1D;  K1 = HID; sA1 = HID; biasp = biasb + NG; }
    hout = HB + (size_t)(pw*2 + 0)*BB*HID; cptr = Cst;
  } else if (layer == 1){
    A0 = h0p; B0 = packW + MSZ;  A1 = h1p; B1 = packW + 2*MSZ; K1 = HID; sA1 = HID;
    biasp = biasb + 2*NG; hout = HB + (size_t)(pw*2 + 1)*BB*HID; cptr = Cst + (size_t)BB*HID;
  } else {
    A0 = h1p; B0 = packW + 3*MSZ; A1 = h2p; B1 = packW + 4*MSZ; K1 = HID; sA1 = HID;
    biasp = biasb + 3*NG; hout = H2A + (size_t)t*BB*HID; cptr = Cst + (size_t)2*BB*HID;
  }
  const int ncmax = 16 + (K1 >> 6);   // 32, or 20 for layer0/gt

  const int rsub = lane >> 3;
  const int kxe  = ((lane & 7) ^ rsub) * 8;   // XOR-swizzled k-chunk (elements)
  const int m_w = w*32, c15 = lane&15, quad = lane>>4;

  // ---- A staging: per-wave-private rows [w*32, w*32+32), 4 buffers of 4KB ----
  auto issueA = [&](int ci, int buf){
    const f16* src; int strd;
    if (ci < 16){ src = A0 + (size_t)ci*64;      strd = HID; }
    else        { src = A1 + (size_t)(ci-16)*64; strd = sA1; }
    char* dst = lds + w*16384 + buf*4096;
    #pragma unroll
    for (int q = 0; q < 4; q++)
      async16(dst + q*1024, src + (size_t)(w*32 + q*8 + rsub)*strd + kxe);
  };

  // ---- B direct-to-reg: SGPR bases per col-tile, shared per-lane voffset ----
  const f16* sb0[4]; const f16* sb1[4];
  #pragma unroll
  for (int tj = 0; tj < 4; tj++){
    sb0[tj] = B0 + (size_t)(col0 + tj*16)*HID;
    sb1[tj] = B1 + (size_t)(col0 + tj*16)*K1;
  }
  const unsigned vB0 = (unsigned)(c15*HID*2 + quad*16);
  const unsigned vB1 = (unsigned)(c15*K1*2  + quad*16);

  auto issueB = [&](int ci, f16x8* bf){
    if (ci < 16){
      const int ko = ci*64;
      #pragma unroll
      for (int tj = 0; tj < 4; tj++){
        bf[tj*2+0] = gload(vB0, sb0[tj] + ko);
        bf[tj*2+1] = gload(vB0, sb0[tj] + ko + 32);
      }
    } else {
      const int ko = (ci-16)*64;
      #pragma unroll
      for (int tj = 0; tj < 4; tj++){
        bf[tj*2+0] = gload(vB1, sb1[tj] + ko);
        bf[tj*2+1] = gload(vB1, sb1[tj] + ko + 32);
      }
    }
  };

  f32x4 acc[2][4];
  f32x4 zero = {0.f, 0.f, 0.f, 0.f};
  #pragma unroll
  for (int i = 0; i < 2; i++)
    #pragma unroll
    for (int j = 0; j < 4; j++) acc[i][j] = zero;

  // fragment LDS offsets (phase XOR per-lane const; row&7 == c15&7)
  const unsigned ldsBase = (unsigned)(uintptr_t)lds;
  const unsigned p0 = (unsigned)(( quad      ^ (c15&7)) * 16);
  const unsigned p1 = (unsigned)(((4 + quad) ^ (c15&7)) * 16);
  const unsigned rA0 = (unsigned)((c15) * 128);
  const unsigned rA1 = (unsigned)((16 + c15) * 128);

  // B register buffers, 4 stages x 8 frags (all indexing compile-time)
  f16x8 bbuf[4][8];

  // prologue: stages 0..3 (12 vm-ops each, A-DMA then B-loads)
  issueA(0, 0); issueB(0, bbuf[0]);
  issueA(1, 1); issueB(1, bbuf[1]);
  issueA(2, 2); issueB(2, bbuf[2]);
  issueA(3, 3); issueB(3, bbuf[3]);

#define WAITVM(N, BF) asm volatile("s_waitcnt vmcnt(" #N ")" \
    : "+v"(BF[0]), "+v"(BF[1]), "+v"(BF[2]), "+v"(BF[3]),    \
      "+v"(BF[4]), "+v"(BF[5]), "+v"(BF[6]), "+v"(BF[7]))

#define S_COMPUTE(KK)                                                         \
    const unsigned ab = ldsBase + (unsigned)(w*16384) + (KK*4096u);           \
    f16x8 a0[2], a1[2];                                                       \
    a0[0] = ldsr128(ab + rA0 + p0);                                           \
    a0[1] = ldsr128(ab + rA1 + p0);                                           \
    a1[0] = ldsr128(ab + rA0 + p1);                                           \
    a1[1] = ldsr128(ab + rA1 + p1);                                           \
    asm volatile("s_waitcnt lgkmcnt(2)" : "+v"(a0[0]), "+v"(a0[1]));          \
    _Pragma("unroll")                                                         \
    for (int ti = 0; ti < 2; ti++)                                            \
      _Pragma("unroll")                                                       \
      for (int tj = 0; tj < 4; tj++)                                          \
        acc[ti][tj] = __builtin_amdgcn_mfma_f32_16x16x32_f16(                 \
            a0[ti], bbuf[KK][tj*2+0], acc[ti][tj], 0, 0, 0);                  \
    asm volatile("s_waitcnt lgkmcnt(0)" : "+v"(a1[0]), "+v"(a1[1]));          \
    _Pragma("unroll")                                                         \
    for (int ti = 0; ti < 2; ti++)                                            \
      _Pragma("unroll")                                                       \
      for (int tj = 0; tj < 4; tj++)                                          \
        acc[ti][tj] = __builtin_amdgcn_mfma_f32_16x16x32_f16(                 \
            a1[ti], bbuf[KK][tj*2+1], acc[ti][tj], 0, 0, 0);

  // main loop: iters 0 .. ncmax-5 (ncmax-4 is a multiple of 4)
  for (int c0 = 0; c0 + 4 < ncmax; c0 += 4){
    if ((c0 & 7) == 0) __builtin_amdgcn_s_barrier();   // skew bound only
    { WAITVM(36, bbuf[0]); S_COMPUTE(0); issueA(c0+4, 0); issueB(c0+4, bbuf[0]); }
    { WAITVM(36, bbuf[1]); S_COMPUTE(1); issueA(c0+5, 1); issueB(c0+5, bbuf[1]); }
    { WAITVM(36, bbuf[2]); S_COMPUTE(2); issueA(c0+6, 2); issueB(c0+6, bbuf[2]); }
    { WAITVM(36, bbuf[3]); S_COMPUTE(3); issueA(c0+7, 3); issueB(c0+7, bbuf[3]); }
  }
  // peeled tail: c = ncmax-4 .. ncmax-1 (buffer index = j, no issues)
  { WAITVM(36, bbuf[0]); S_COMPUTE(0); }
  { WAITVM(24, bbuf[1]); S_COMPUTE(1); }
  { WAITVM(12, bbuf[2]); S_COMPUTE(2); }
  { WAITVM(0,  bbuf[3]); S_COMPUTE(3); }

#undef S_COMPUTE
#undef WAITVM

  // ---- fused LSTM cell epilogue (per-lane single activation, shuffle after) ----
  const int gl = lane&3, sbase = lane&60;
  #pragma unroll
  for (int tj = 0; tj < 4; tj++){
    const int ncol = col0 + tj*16 + c15;
    const int unit = ncol >> 2;
    const float bn = biasp[ncol];
    float cp[8];
    #pragma unroll
    for (int ti = 0; ti < 2; ti++)
      #pragma unroll
      for (int r = 0; r < 4; r++)
        cp[ti*4 + r] = cptr[(size_t)(m_w + ti*16 + quad*4 + r)*HID + unit];
    #pragma unroll
    for (int ti = 0; ti < 2; ti++){
      f32x4 v = acc[ti][tj];
      #pragma unroll
      for (int r = 0; r < 4; r++){
        float x   = v[r] + bn;
        float act = (gl == 2) ? tanh_fast(x) : sigf(x);   // lane's own gate only
        float iv = __shfl(act, sbase);
        float fv = __shfl(act, sbase + 1);
        float gv = __shfl(act, sbase + 2);
        float ov = __shfl(act, sbase + 3);
        float cn = fmaf(fv, cp[ti*4 + r], iv*gv);
        float hn = ov * tanh_fast(cn);
        int m = m_w + ti*16 + quad*4 + r;
        if (gl == 0)      cptr[(size_t)m*HID + unit] = cn;
        else if (gl == 1) hout[(size_t)m*HID + unit] = (f16)hn;
      }
    }
  }
}

// ================= final output GEMM =================
__global__ __launch_bounds__(256, 2) void k_final(const char* __restrict__ ws,
                                                  const float* __restrict__ bd,
                                                  float* __restrict__ dout)
{
  __shared__ __align__(16) char ldsA[16384];
  __shared__ __align__(16) char ldsB[16384];
  const int w = threadIdx.x >> 6, lane = threadIdx.x & 63;
  const int n0 = blockIdx.x*128, m0 = blockIdx.y*128;
  const f16* A  = (const f16*)(ws + OFF_H2ALL);
  const f16* Bp = (const f16*)(ws + OFF_WD);

  f32x4 acc[4][4];
  f32x4 zero = {0.f, 0.f, 0.f, 0.f};
  #pragma unroll
  for (int i = 0; i < 4; i++)
    #pragma unroll
    for (int j = 0; j < 4; j++) acc[i][j] = zero;

  gemm_tile(acc, A, m0, HID, Bp, n0, HID, ldsA, ldsB, w, lane);

  const int m_w = (w>>1)*64, n_w = (w&1)*64, quad = lane>>4, c15 = lane&15;
  #pragma unroll
  for (int tj = 0; tj < 4; tj++){
    int o = n0 + n_w + tj*16 + c15;
    bool valid = (o < 227);
    float bn = valid ? bd[o] : 0.f;
    #pragma unroll
    for (int ti = 0; ti < 4; ti++){
      f32x4 v = acc[ti][tj];
      #pragma unroll
      for (int r = 0; r < 4; r++){
        int m = m0 + m_w + ti*16 + quad*4 + r;
        if (valid){
          int tt = m >> 8, b = m & 255;
          dout[(size_t)b*22700 + (size_t)tt*227 + o] = v[r] + bn;
        }
      }
    }
  }
}

// ================= host =================
extern "C" void kernel_launch(void* const* d_in, const int* in_sizes, int n_in,
                              void* d_out, int out_size, void* d_ws, size_t ws_size,
                              hipStream_t stream)
{
  (void)in_sizes; (void)n_in; (void)out_size; (void)ws_size;
  const float* seq  = (const float*)d_in[0];
  const float* Wih1 = (const float*)d_in[1];
  const float* Whh1 = (const float*)d_in[2];
  const float* bih1 = (const float*)d_in[3];
  const float* bhh1 = (const float*)d_in[4];
  const float* Wih2 = (const float*)d_in[5];
  const float* Whh2 = (const float*)d_in[6];
  const float* bih2 = (const float*)d_in[7];
  const float* bhh2 = (const float*)d_in[8];
  const float* Wih3 = (const float*)d_in[9];
  const float* Whh3 = (const float*)d_in[10];
  const float* bih3 = (const float*)d_in[11];
  const float* bhh3 = (const float*)d_in[12];
  const float* Wd   = (const float*)d_in[13];
  const float* bd   = (const float*)d_in[14];
  char* ws = (char*)d_ws;

  hipMemsetAsync(ws + OFF_C,    0, (size_t)3*BB*HID*4, stream);
  hipMemsetAsync(ws + OFF_HBUF, 0, (size_t)2*BB*HID*2, stream);
  hipMemsetAsync(ws + OFF_H2Z,  0, (size_t)BB*HID*2,   stream);

  k_pack5   <<<dim3(2048, 5), dim3(256), 0, stream>>>(Whh1, Wih2, Whh2, Wih3, Whh3, ws);
  k_packwih1<<<dim3(4096),    dim3(256), 0, stream>>>(Wih1, ws);
  k_packwd  <<<dim3(256),     dim3(256), 0, stream>>>(Wd, ws);
  k_packwdt <<<dim3(1024),    dim3(256), 0, stream>>>(Wd, ws);
  k_xpad    <<<dim3(25600),   dim3(256), 0, stream>>>(seq, ws);
  k_bias    <<<dim3(16),      dim3(256), 0, stream>>>(bih1, bhh1, bih2, bhh2, bih3, bhh3, Wih1, bd, ws);
  k_w1d     <<<dim3(8, 32),   dim3(256), 0, stream>>>(ws);

  for (int t = 0; t < TT; t++){
    int ug = ((t % 10) < 5) ? 1 : 0;
    k_step<<<dim3(64, 3), dim3(512), 0, stream>>>(ws, t, ug);
  }

  k_final<<<dim3(2, 200), dim3(256), 0, stream>>>((const char*)ws, bd, (float*)d_out);
}

// Round 4
// 3115.249 us; speedup vs baseline: 2.4450x; 2.4450x over previous
//
#include <hip/hip_runtime.h>
#include <cstdint>

typedef _Float16 f16;
typedef _Float16 f16x8 __attribute__((ext_vector_type(8)));
typedef float    f32x4 __attribute__((ext_vector_type(4)));

#define DINL __device__ __forceinline__

static constexpr int HID = 1024;
static constexpr int NG  = 4096;   // 4*HID gate count
static constexpr int BB  = 256;    // batch
static constexpr int TT  = 100;    // seq len
static constexpr int KX  = 256;    // padded input-feature K (227 -> 256)
static constexpr size_t MSZ = (size_t)NG * HID;   // halves per packed [4096][1024] mat

// ---- workspace layout (bytes). total ~119 MiB ----
static constexpr size_t OFF_PACKW5 = 0;
static constexpr size_t OFF_W1D    = OFF_PACKW5 + 5*MSZ*2;
static constexpr size_t OFF_WIH1   = OFF_W1D   + MSZ*2;
static constexpr size_t OFF_WD     = OFF_WIH1  + (size_t)NG*KX*2;
static constexpr size_t OFF_XPAD   = OFF_WD    + (size_t)256*HID*2;
static constexpr size_t OFF_BIAS   = OFF_XPAD  + (size_t)TT*BB*KX*2;
static constexpr size_t OFF_C      = OFF_BIAS  + (size_t)4*NG*4;
static constexpr size_t OFF_HBUF   = OFF_C     + (size_t)3*BB*HID*4;
static constexpr size_t OFF_H2Z    = OFF_HBUF  + (size_t)4*BB*HID*2;
static constexpr size_t OFF_H2ALL  = OFF_H2Z   + (size_t)BB*HID*2;
// WdT scratch ([1024][256] f16) lives at OFF_H2ALL until k_w1d consumes it.

DINL void async16(void* lds, const void* g){
  auto lp = reinterpret_cast<__attribute__((address_space(3))) unsigned int*>(
      reinterpret_cast<uintptr_t>(lds));
  auto gp = reinterpret_cast<const __attribute__((address_space(1))) unsigned int*>(
      reinterpret_cast<uintptr_t>(g));
  __builtin_amdgcn_global_load_lds(gp, lp, 16, 0, 0);
}

// LDS read via inline asm: invisible to the compiler's LDS-DMA waitcnt pass
// (prevents it from inserting s_waitcnt vmcnt(0) before aliasing ds_reads).
DINL f16x8 ldsr128(unsigned a){
  f16x8 r;
  asm volatile("ds_read_b128 %0, %1" : "=v"(r) : "v"(a));
  return r;
}

DINL float sigf(float x){
  x = fminf(fmaxf(x, -30.f), 30.f);
  return __fdividef(1.f, 1.f + __expf(-x));
}
DINL float tanh_fast(float x){
  x = fminf(fmaxf(x, -15.f), 15.f);
  float t = __expf(2.f*x);
  return __fdividef(t - 1.f, t + 1.f);
}

// ---- single-buffered 128x128 tile core (k_w1d / k_final only) ----
DINL void gemm_tile(f32x4 acc[4][4],
                    const f16* __restrict__ A, int m0, int sA,
                    const f16* __restrict__ Bp, int n0, int K,
                    char* ldsA, char* ldsB, int w, int lane)
{
  const int m_w = (w>>1)*64, n_w = (w&1)*64, c15 = lane&15;
  for (int k0 = 0; k0 < K; k0 += 64){
    __syncthreads();
    #pragma unroll
    for (int q = 0; q < 4; q++){
      int r0  = w*32 + q*8;
      int row = r0 + (lane>>3);
      int kg  = (lane&7) ^ (row&7);
      async16(ldsA + r0*128, A  + (size_t)(m0+row)*sA + k0 + kg*8);
      async16(ldsB + r0*128, Bp + (size_t)(n0+row)*K  + k0 + kg*8);
    }
    __syncthreads();
    #pragma unroll
    for (int kw = 0; kw < 2; kw++){
      f16x8 af[4], bf[4];
      #pragma unroll
      for (int ti = 0; ti < 4; ti++){
        int row  = m_w + ti*16 + c15;
        int phys = (kw*4 + (lane>>4)) ^ (row&7);
        af[ti] = *(const f16x8*)(ldsA + row*128 + phys*16);
      }
      #pragma unroll
      for (int tj = 0; tj < 4; tj++){
        int row  = n_w + tj*16 + c15;
        int phys = (kw*4 + (lane>>4)) ^ (row&7);
        bf[tj] = *(const f16x8*)(ldsB + row*128 + phys*16);
      }
      #pragma unroll
      for (int ti = 0; ti < 4; ti++)
        #pragma unroll
        for (int tj = 0; tj < 4; tj++)
          acc[ti][tj] = __builtin_amdgcn_mfma_f32_16x16x32_f16(af[ti], bf[tj], acc[ti][tj], 0, 0, 0);
    }
  }
}

// ================= prep kernels =================

__global__ void k_pack5(const float* W0, const float* W1, const float* W2,
                        const float* W3, const float* W4, char* ws)
{
  f16* dst = (f16*)(ws + OFF_PACKW5);
  const int mat = blockIdx.y;
  const float* src = mat==0?W0 : mat==1?W1 : mat==2?W2 : mat==3?W3 : W4;
  int tid = blockIdx.x*256 + threadIdx.x;
  int n = tid >> 7, kc = tid & 127;
  int r = ((n&3) << 10) + (n >> 2);
  const float* s = src + (size_t)r*HID + kc*8;
  f16x8 o;
  #pragma unroll
  for (int i = 0; i < 8; i++) o[i] = (f16)s[i];
  *(f16x8*)(dst + (size_t)mat*MSZ + (size_t)n*HID + kc*8) = o;
}

__global__ void k_packwih1(const float* __restrict__ Wih1, char* ws){
  f16* dst = (f16*)(ws + OFF_WIH1);
  int n = blockIdx.x, k = threadIdx.x;
  int r = ((n&3) << 10) + (n >> 2);
  dst[(size_t)n*KX + k] = (k < 227) ? (f16)Wih1[(size_t)r*227 + k] : (f16)0.f;
}

__global__ void k_packwd(const float* __restrict__ Wd, char* ws){
  f16* dst = (f16*)(ws + OFF_WD);
  int o = blockIdx.x;
  #pragma unroll
  for (int j = 0; j < 4; j++){
    int k = threadIdx.x + j*256;
    dst[(size_t)o*HID + k] = (o < 227) ? (f16)Wd[(size_t)o*HID + k] : (f16)0.f;
  }
}

__global__ void k_packwdt(const float* __restrict__ Wd, char* ws){
  f16* dst = (f16*)(ws + OFF_H2ALL);
  int h = blockIdx.x, o = threadIdx.x;
  dst[(size_t)h*KX + o] = (o < 227) ? (f16)Wd[(size_t)o*HID + h] : (f16)0.f;
}

__global__ void k_xpad(const float* __restrict__ seq, char* ws){
  f16* dst = (f16*)(ws + OFF_XPAD);
  int idx = blockIdx.x*256 + threadIdx.x;
  int t = idx >> 16, rem = idx & 65535, b = rem >> 8, k = rem & 255;
  dst[idx] = (k < 227) ? (f16)seq[(size_t)b*22700 + (size_t)t*227 + k] : (f16)0.f;
}

__global__ void k_bias(const float* bih1, const float* bhh1, const float* bih2, const float* bhh2,
                       const float* bih3, const float* bhh3, const float* Wih1, const float* bd,
                       char* ws)
{
  int n = blockIdx.x*256 + threadIdx.x;
  if (n >= NG) return;
  int r = ((n&3) << 10) + (n >> 2);
  float* b = (float*)(ws + OFF_BIAS);
  float bf = bih1[r] + bhh1[r];
  float s = 0.f;
  for (int o = 0; o < 227; o++) s += Wih1[(size_t)r*227 + o] * bd[o];
  b[n]        = bf;
  b[NG + n]   = bf + s;
  b[2*NG + n] = bih2[r] + bhh2[r];
  b[3*NG + n] = bih3[r] + bhh3[r];
}

__global__ __launch_bounds__(256, 2) void k_w1d(char* ws)
{
  __shared__ __align__(16) char ldsA[16384];
  __shared__ __align__(16) char ldsB[16384];
  const int w = threadIdx.x >> 6, lane = threadIdx.x & 63;
  const int n0 = blockIdx.x*128, m0 = blockIdx.y*128;
  const f16* A  = (const f16*)(ws + OFF_WIH1);
  const f16* Bp = (const f16*)(ws + OFF_H2ALL);
  f16* W1D = (f16*)(ws + OFF_W1D);

  f32x4 acc[4][4];
  f32x4 zero = {0.f, 0.f, 0.f, 0.f};
  #pragma unroll
  for (int i = 0; i < 4; i++)
    #pragma unroll
    for (int j = 0; j < 4; j++) acc[i][j] = zero;

  gemm_tile(acc, A, m0, KX, Bp, n0, KX, ldsA, ldsB, w, lane);

  const int m_w = (w>>1)*64, n_w = (w&1)*64, quad = lane>>4, c15 = lane&15;
  #pragma unroll
  for (int tj = 0; tj < 4; tj++){
    int col = n0 + n_w + tj*16 + c15;
    #pragma unroll
    for (int ti = 0; ti < 4; ti++){
      f32x4 v = acc[ti][tj];
      #pragma unroll
      for (int r = 0; r < 4; r++){
        int m = m0 + m_w + ti*16 + quad*4 + r;
        W1D[(size_t)m*HID + col] = (f16)v[r];
      }
    }
  }
}

// ================= recurrent step kernel =================
// grid (64 ntiles, 3 layers), 512 threads = 8 waves (2/SIMD).
// Tm=256 x Tn=64, BK=64; wave tile 32x64 (per-wave-private A rows).
// LDS (160KB): [0,64K) B ring 8 slabs x 8KB; [64K,160K) per-wave 3x4KB A bufs.
// Software-pipelined fragments (read-ahead 1, two register banks): at iter c,
// issue the 12 ds_reads for chunk c+1, wait lgkmcnt(12) (forces chunk-c reads
// done, leaves c+1 in flight), run 16 MFMAs on bank(c). ds_read latency hides
// under the MFMAs. Group boundaries moved to c%4==3 (publishing group (c+1)/4):
// lgkmcnt(0) drain BEFORE the barrier closes the race between retiring-group
// ds_reads (in flight past the barrier) and the incoming group's DMA writes.
// vm schedule (per wave, order B-issue then A-issue within an iter):
//   steady vmcnt(4); c%4==0 && 4<=c<=ncmax-8 -> vmcnt(8); c=ncmax-2 -> 0.
// A prefetch distance 3 (bufs 3-deep); B groups published 4-7 chunks ahead.
__global__ __launch_bounds__(512, 2) void k_step(char* __restrict__ ws, int t, int use_gt)
{
  __shared__ __align__(16) char lds[163840];
  const int w = threadIdx.x >> 6, lane = threadIdx.x & 63;
  const int col0 = blockIdx.x*64, layer = blockIdx.y;

  const f16* packW = (const f16*)(ws + OFF_PACKW5);
  const f16* W1D   = (const f16*)(ws + OFF_W1D);
  const f16* WIH1  = (const f16*)(ws + OFF_WIH1);
  const f16* XP    = (const f16*)(ws + OFF_XPAD) + (size_t)t*BB*KX;
  const float* biasb = (const float*)(ws + OFF_BIAS);
  float* Cst = (float*)(ws + OFF_C);
  f16* HB  = (f16*)(ws + OFF_HBUF);
  f16* H2Z = (f16*)(ws + OFF_H2Z);
  f16* H2A = (f16*)(ws + OFF_H2ALL);

  const int pr = t & 1, pw = pr ^ 1;
  const f16* h0p = HB + (size_t)(pr*2 + 0)*BB*HID;
  const f16* h1p = HB + (size_t)(pr*2 + 1)*BB*HID;
  const f16* h2p = (t == 0) ? H2Z : (H2A + (size_t)(t-1)*BB*HID);

  const f16 *A0, *A1, *B0, *B1; int K1, sA1;
  const float* biasp; f16* hout; float* cptr;
  if (layer == 0){
    A0 = h0p; B0 = packW;
    if (use_gt){ A1 = XP;  B1 = WIH1; K1 = KX;  sA1 = KX;  biasp = biasb; }
    else       { A1 = h2p; B1 = W1D;  K1 = HID; sA1 = HID; biasp = biasb + NG; }
    hout = HB + (size_t)(pw*2 + 0)*BB*HID; cptr = Cst;
  } else if (layer == 1){
    A0 = h0p; B0 = packW + MSZ;  A1 = h1p; B1 = packW + 2*MSZ; K1 = HID; sA1 = HID;
    biasp = biasb + 2*NG; hout = HB + (size_t)(pw*2 + 1)*BB*HID; cptr = Cst + (size_t)BB*HID;
  } else {
    A0 = h1p; B0 = packW + 3*MSZ; A1 = h2p; B1 = packW + 4*MSZ; K1 = HID; sA1 = HID;
    biasp = biasb + 3*NG; hout = H2A + (size_t)t*BB*HID; cptr = Cst + (size_t)2*BB*HID;
  }
  const int ncmax = 16 + (K1 >> 6);   // 32, or 20 for layer0/gt

  const int rsub = lane >> 3;
  const int kxe  = ((lane & 7) ^ rsub) * 8;   // XOR-swizzled k-chunk (elements)
  const int m_w = w*32, c15 = lane&15, quad = lane>>4;

  // A: per-wave-private rows [w*32, w*32+32), 3 buffers of 4KB at 64K + w*12KB
  auto issueA = [&](int ci, int buf){
    const f16* src; int strd;
    if (ci < 16){ src = A0 + (size_t)ci*64;      strd = HID; }
    else        { src = A1 + (size_t)(ci-16)*64; strd = sA1; }
    char* dst = lds + 65536 + w*12288 + buf*4096;
    #pragma unroll
    for (int q = 0; q < 4; q++)
      async16(dst + q*1024, src + (size_t)(w*32 + q*8 + rsub)*strd + kxe);
  };
  // B: shared ring of 8 chunk-slabs (8KB each); wave w covers chunk base+(w>>1)
  auto issueB = [&](int chunk, int j){
    const f16* src; int strd;
    if (chunk < 16){ src = B0 + (size_t)chunk*64;      strd = HID; }
    else           { src = B1 + (size_t)(chunk-16)*64; strd = K1;  }
    async16(lds + (chunk & 7)*8192 + j*1024,
            src + (size_t)(col0 + j*8 + rsub)*strd + kxe);
  };

  f32x4 acc[2][4];
  f32x4 zero = {0.f, 0.f, 0.f, 0.f};
  #pragma unroll
  for (int i = 0; i < 2; i++)
    #pragma unroll
    for (int j = 0; j < 4; j++) acc[i][j] = zero;

  // fragment LDS offsets; (row&7)==(c15&7) -> swizzle phase per-lane const
  const unsigned ldsBase = (unsigned)(uintptr_t)lds;
  const unsigned aBase   = ldsBase + 65536u + (unsigned)(w*12288);
  const unsigned p0 = (unsigned)(( quad      ^ (c15&7)) * 16);
  const unsigned p1 = (unsigned)(((4 + quad) ^ (c15&7)) * 16);
  const unsigned rA0 = (unsigned)(( 0 + c15) * 128);
  const unsigned rA1 = (unsigned)((16 + c15) * 128);
  const unsigned rB0 = (unsigned)(( 0 + c15) * 128);
  const unsigned rB1 = (unsigned)((16 + c15) * 128);
  const unsigned rB2 = (unsigned)((32 + c15) * 128);
  const unsigned rB3 = (unsigned)((48 + c15) * 128);

  // two register banks of 12 fragments each
  f16x8 fA0[2][2], fB0[2][4], fA1[2][2], fB1[2][4];

#define DS12(NX)                                                   \
    { const unsigned sN = ldsBase + (unsigned)((((c+1)&7))*8192);  \
      const unsigned aN = aBase + (unsigned)(bufN*4096);           \
      fA0[NX][0] = ldsr128(aN + rA0 + p0);                         \
      fA0[NX][1] = ldsr128(aN + rA1 + p0);                         \
      fB0[NX][0] = ldsr128(sN + rB0 + p0);                         \
      fB0[NX][1] = ldsr128(sN + rB1 + p0);                         \
      fB0[NX][2] = ldsr128(sN + rB2 + p0);                         \
      fB0[NX][3] = ldsr128(sN + rB3 + p0);                         \
      fA1[NX][0] = ldsr128(aN + rA0 + p1);                         \
      fA1[NX][1] = ldsr128(aN + rA1 + p1);                         \
      fB1[NX][0] = ldsr128(sN + rB0 + p1);                         \
      fB1[NX][1] = ldsr128(sN + rB1 + p1);                         \
      fB1[NX][2] = ldsr128(sN + rB2 + p1);                         \
      fB1[NX][3] = ldsr128(sN + rB3 + p1); }

#define TIES(BK) "+v"(fA0[BK][0]), "+v"(fA0[BK][1]),               \
    "+v"(fB0[BK][0]), "+v"(fB0[BK][1]), "+v"(fB0[BK][2]), "+v"(fB0[BK][3]), \
    "+v"(fA1[BK][0]), "+v"(fA1[BK][1]),                            \
    "+v"(fB1[BK][0]), "+v"(fB1[BK][1]), "+v"(fB1[BK][2]), "+v"(fB1[BK][3])

#define MFMA16(BK)                                                 \
    _Pragma("unroll")                                              \
    for (int ti = 0; ti < 2; ti++)                                 \
      _Pragma("unroll")                                            \
      for (int tj = 0; tj < 4; tj++)                               \
        acc[ti][tj] = __builtin_amdgcn_mfma_f32_16x16x32_f16(      \
            fA0[BK][ti], fB0[BK][tj], acc[ti][tj], 0, 0, 0);       \
    _Pragma("unroll")                                              \
    for (int ti = 0; ti < 2; ti++)                                 \
      _Pragma("unroll")                                            \
      for (int tj = 0; tj < 4; tj++)                               \
        acc[ti][tj] = __builtin_amdgcn_mfma_f32_16x16x32_f16(      \
            fA1[BK][ti], fB1[BK][tj], acc[ti][tj], 0, 0, 0);

#define ADV { bufA = bufN; bufN = (bufN==2)?0:bufN+1; ++c; }

// non-boundary iter (c%4 != 3): VMN literal wait
#define ITER_N(VMN, CUR, NX)                                       \
  { asm volatile("s_waitcnt vmcnt(" #VMN ")" ::: "memory");        \
    DS12(NX);                                                      \
    asm volatile("s_waitcnt lgkmcnt(12)" : TIES(CUR));             \
    issueA(c+3, bufA);                                             \
    MFMA16(CUR); ADV; }

// boundary iter (c%4 == 3): drain lgkm, barrier, publish group (c+1)/4 + 1
#define ITER_X(CUR, NX)                                            \
  { asm volatile("s_waitcnt vmcnt(4)" ::: "memory");               \
    asm volatile("s_waitcnt lgkmcnt(0)" : TIES(CUR));              \
    __builtin_amdgcn_s_barrier();                                  \
    __builtin_amdgcn_sched_barrier(0);                             \
    DS12(NX);                                                      \
    if (c <= ncmax-9){                                             \
      const int ch = 4*(((c+1)>>2)+1) + (w>>1), jb = (w&1)*4;      \
      issueB(ch, jb+0); issueB(ch, jb+1);                          \
      issueB(ch, jb+2); issueB(ch, jb+3);                          \
    }                                                              \
    issueA(c+3, bufA);                                             \
    MFMA16(CUR); ADV; }

  // ---- prologue: B groups 0,1 + A chunks 0,1,2; then DS(0) ----
  {
    const int jb = (w & 1) * 4, cb = w >> 1;
    #pragma unroll
    for (int k = 0; k < 4; k++) issueB(cb, jb + k);
    #pragma unroll
    for (int k = 0; k < 4; k++) issueB(4 + cb, jb + k);
  }
  issueA(0, 0); issueA(1, 1); issueA(2, 2);
  asm volatile("s_waitcnt vmcnt(8)" ::: "memory");   // own Bg0,Bg1,A0 done
  __builtin_amdgcn_s_barrier();                      // collective Bg0,Bg1
  __builtin_amdgcn_sched_barrier(0);

  int c = -1, bufA = 0, bufN = 0;
  DS12(0);                                           // DS(0): slab 0, A-buf 0
  c = 0; bufA = 0; bufN = 1;

  // group 0 (c = 0..3): vmcnt(4) at c=0 (prologue B older than A1)
  ITER_N(4, 0, 1)
  ITER_N(4, 1, 0)
  ITER_N(4, 0, 1)
  ITER_X(   1, 0)
  // groups 1 .. (ncmax/4 - 2): c = 4 .. ncmax-5
  for (int g = 1; g <= (ncmax >> 2) - 2; ++g){
    ITER_N(8, 0, 1)
    ITER_N(4, 1, 0)
    ITER_N(4, 0, 1)
    ITER_X(   1, 0)
  }
  // tail: c = ncmax-4 .. ncmax-1
  { asm volatile("s_waitcnt vmcnt(4)" ::: "memory");
    DS12(1);
    asm volatile("s_waitcnt lgkmcnt(12)" : TIES(0));
    issueA(c+3, bufA);
    MFMA16(0); ADV; }
  { asm volatile("s_waitcnt vmcnt(4)" ::: "memory");
    DS12(0);
    asm volatile("s_waitcnt lgkmcnt(12)" : TIES(1));
    MFMA16(1); ADV; }
  { asm volatile("s_waitcnt vmcnt(0)" ::: "memory");
    DS12(1);
    asm volatile("s_waitcnt lgkmcnt(12)" : TIES(0));
    MFMA16(0); ADV; }
  { asm volatile("s_waitcnt lgkmcnt(0)" : TIES(1));
    MFMA16(1); }

#undef ITER_X
#undef ITER_N
#undef ADV
#undef MFMA16
#undef TIES
#undef DS12

  // ---- fused LSTM cell epilogue (per-lane single activation, shuffle after) ----
  const int gl = lane&3, sbase = lane&60;
  #pragma unroll
  for (int tj = 0; tj < 4; tj++){
    const int ncol = col0 + tj*16 + c15;
    const int unit = ncol >> 2;
    const float bn = biasp[ncol];
    float cp[8];
    #pragma unroll
    for (int ti = 0; ti < 2; ti++)
      #pragma unroll
      for (int r = 0; r < 4; r++)
        cp[ti*4 + r] = cptr[(size_t)(m_w + ti*16 + quad*4 + r)*HID + unit];
    #pragma unroll
    for (int ti = 0; ti < 2; ti++){
      f32x4 v = acc[ti][tj];
      #pragma unroll
      for (int r = 0; r < 4; r++){
        float x   = v[r] + bn;
        float act = (gl == 2) ? tanh_fast(x) : sigf(x);   // lane's own gate only
        float iv = __shfl(act, sbase);
        float fv = __shfl(act, sbase + 1);
        float gv = __shfl(act, sbase + 2);
        float ov = __shfl(act, sbase + 3);
        float cn = fmaf(fv, cp[ti*4 + r], iv*gv);
        float hn = ov * tanh_fast(cn);
        int m = m_w + ti*16 + quad*4 + r;
        if (gl == 0)      cptr[(size_t)m*HID + unit] = cn;
        else if (gl == 1) hout[(size_t)m*HID + unit] = (f16)hn;
      }
    }
  }
}

// ================= final output GEMM =================
__global__ __launch_bounds__(256, 2) void k_final(const char* __restrict__ ws,
                                                  const float* __restrict__ bd,
                                                  float* __restrict__ dout)
{
  __shared__ __align__(16) char ldsA[16384];
  __shared__ __align__(16) char ldsB[16384];
  const int w = threadIdx.x >> 6, lane = threadIdx.x & 63;
  const int n0 = blockIdx.x*128, m0 = blockIdx.y*128;
  const f16* A  = (const f16*)(ws + OFF_H2ALL);
  const f16* Bp = (const f16*)(ws + OFF_WD);

  f32x4 acc[4][4];
  f32x4 zero = {0.f, 0.f, 0.f, 0.f};
  #pragma unroll
  for (int i = 0; i < 4; i++)
    #pragma unroll
    for (int j = 0; j < 4; j++) acc[i][j] = zero;

  gemm_tile(acc, A, m0, HID, Bp, n0, HID, ldsA, ldsB, w, lane);

  const int m_w = (w>>1)*64, n_w = (w&1)*64, quad = lane>>4, c15 = lane&15;
  #pragma unroll
  for (int tj = 0; tj < 4; tj++){
    int o = n0 + n_w + tj*16 + c15;
    bool valid = (o < 227);
    float bn = valid ? bd[o] : 0.f;
    #pragma unroll
    for (int ti = 0; ti < 4; ti++){
      f32x4 v = acc[ti][tj];
      #pragma unroll
      for (int r = 0; r < 4; r++){
        int m = m0 + m_w + ti*16 + quad*4 + r;
        if (valid){
          int tt = m >> 8, b = m & 255;
          dout[(size_t)b*22700 + (size_t)tt*227 + o] = v[r] + bn;
        }
      }
    }
  }
}

// ================= host =================
extern "C" void kernel_launch(void* const* d_in, const int* in_sizes, int n_in,
                              void* d_out, int out_size, void* d_ws, size_t ws_size,
                              hipStream_t stream)
{
  (void)in_sizes; (void)n_in; (void)out_size; (void)ws_size;
  const float* seq  = (const float*)d_in[0];
  const float* Wih1 = (const float*)d_in[1];
  const float* Whh1 = (const float*)d_in[2];
  const float* bih1 = (const float*)d_in[3];
  const float* bhh1 = (const float*)d_in[4];
  const float* Wih2 = (const float*)d_in[5];
  const float* Whh2 = (const float*)d_in[6];
  const float* bih2 = (const float*)d_in[7];
  const float* bhh2 = (const float*)d_in[8];
  const float* Wih3 = (const float*)d_in[9];
  const float* Whh3 = (const float*)d_in[10];
  const float* bih3 = (const float*)d_in[11];
  const float* bhh3 = (const float*)d_in[12];
  const float* Wd   = (const float*)d_in[13];
  const float* bd   = (const float*)d_in[14];
  char* ws = (char*)d_ws;

  hipMemsetAsync(ws + OFF_C,    0, (size_t)3*BB*HID*4, stream);
  hipMemsetAsync(ws + OFF_HBUF, 0, (size_t)2*BB*HID*2, stream);
  hipMemsetAsync(ws + OFF_H2Z,  0, (size_t)BB*HID*2,   stream);

  k_pack5   <<<dim3(2048, 5), dim3(256), 0, stream>>>(Whh1, Wih2, Whh2, Wih3, Whh3, ws);
  k_packwih1<<<dim3(4096),    dim3(256), 0, stream>>>(Wih1, ws);
  k_packwd  <<<dim3(256),     dim3(256), 0, stream>>>(Wd, ws);
  k_packwdt <<<dim3(1024),    dim3(256), 0, stream>>>(Wd, ws);
  k_xpad    <<<dim3(25600),   dim3(256), 0, stream>>>(seq, ws);
  k_bias    <<<dim3(16),      dim3(256), 0, stream>>>(bih1, bhh1, bih2, bhh2, bih3, bhh3, Wih1, bd, ws);
  k_w1d     <<<dim3(8, 32),   dim3(256), 0, stream>>>(ws);

  for (int t = 0; t < TT; t++){
    int ug = ((t % 10) < 5) ? 1 : 0;
    k_step<<<dim3(64, 3), dim3(512), 0, stream>>>(ws, t, ug);
  }

  k_final<<<dim3(2, 200), dim3(256), 0, stream>>>((const char*)ws, bd, (float*)d_out);
}